// Round 16
// baseline (270.810 us; speedup 1.0000x reference)
//
#include <hip/hip_runtime.h>
#include <hip/hip_bf16.h>
#include <math.h>

// Sizes: B=16, N=64, nE=128, H=128, LAT=128, NS=64, NV=32, INV=96, D_NODE=160
#define SQRT3F 1.7320508075688772f
#define ALPHAF 0.10206207261596577f  // 1/sqrt(96)
#define PIF 3.14159265358979323846f

typedef short v8s __attribute__((ext_vector_type(8)));
typedef float v4f __attribute__((ext_vector_type(4)));

__device__ __forceinline__ float silu_f(float x) {
  return x / (1.0f + __expf(-x));
}
__device__ __forceinline__ float sigmoid_f(float x) {
  return 1.0f / (1.0f + __expf(-x));
}
__device__ __forceinline__ unsigned short f2bf(float f) {
  unsigned int u = __float_as_uint(f);
  unsigned int r = (u + 0x7fffu + ((u >> 16) & 1u)) >> 16;
  return (unsigned short)r;
}
__device__ __forceinline__ float bf2f(unsigned short h) {
  return __uint_as_float(((unsigned int)h) << 16);
}
__device__ __forceinline__ void split_trunc(float x, short* h, short* l) {
  unsigned int u = __float_as_uint(x);
  unsigned short hs = (unsigned short)(u >> 16);
  float r = x - __uint_as_float((unsigned int)hs << 16);
  *h = (short)hs;
  *l = (short)(__float_as_uint(r) >> 16);
}

__device__ __forceinline__ void pack_frag(const float* __restrict__ W, int s0,
                                          unsigned short* __restrict__ fh,
                                          unsigned short* __restrict__ fl) {
  const int lane = s0 & 63;
  const int t = (s0 >> 6) & 7;
  const int ks = s0 >> 9;
  const int kbase = ks * 32 + (lane >> 4) * 8;
  const int n = t * 16 + (lane & 15);
  unsigned short hv[8], lv[8];
  #pragma unroll
  for (int j = 0; j < 8; ++j) {
    float w = W[(size_t)(kbase + j) * 128 + n];
    unsigned short h = f2bf(w);
    hv[j] = h;
    lv[j] = f2bf(w - bf2f(h));
  }
  *(uint4*)&fh[(size_t)s0 * 8] = *(uint4*)hv;
  *(uint4*)&fl[(size_t)s0 * 8] = *(uint4*)lv;
}

// ---------------------------------------------------------------------------
// K_FRONT: merged castw2 (blocks 0..575) + prep (576..1087, 2 nodes/block)
// + castw1/packout/Pe (1088..1181). One launch instead of three.
// ---------------------------------------------------------------------------
__global__ void __launch_bounds__(256) k_front(
    const float* __restrict__ W2, unsigned short* __restrict__ W2fh,
    unsigned short* __restrict__ W2fl,
    const float* __restrict__ hf, const int* __restrict__ z,
    const float* __restrict__ pos, const float* __restrict__ z_emb,
    const float* __restrict__ vwW0, const float* __restrict__ vwb0,
    const float* __restrict__ vwW1, const float* __restrict__ vwb1,
    const float* __restrict__ scW0,
    unsigned short* __restrict__ hTh, unsigned short* __restrict__ hTl,
    float* __restrict__ Pn, float* __restrict__ Pa,
    float* __restrict__ xvu, float* __restrict__ y1cw,
    const float* __restrict__ scW1,
    unsigned short* __restrict__ W1fh, unsigned short* __restrict__ W1fl,
    const float* __restrict__ oW0, const float* __restrict__ oW1,
    const float* __restrict__ oW2,
    unsigned short* __restrict__ O0h, unsigned short* __restrict__ O0l,
    unsigned short* __restrict__ O1h, unsigned short* __restrict__ O1l,
    unsigned short* __restrict__ O2h, unsigned short* __restrict__ O2l,
    const float* __restrict__ e_feat, const float* __restrict__ scb0,
    float* __restrict__ Pe) {
  const int bid = blockIdx.x;
  const int tid = threadIdx.x;
  __shared__ float S[2304];

  if (bid < 576) {
    // ---- castw2 ----
    const int T = bid;
    float (*Tl)[17] = (float(*)[17])S;
    for (int idx = tid; idx < 2048; idx += 256) {
      int k = idx >> 4, cc = idx & 15;
      Tl[k][cc] = W2[(size_t)k * 9216 + T * 16 + cc];
    }
    __syncthreads();
    const int ks = tid >> 6, lane = tid & 63;
    const int q = lane >> 4, cq = lane & 15;
    const int k0 = ks * 32 + q * 8;
    unsigned short hv[8], lv[8];
    #pragma unroll
    for (int j = 0; j < 8; ++j) {
      float wv = Tl[k0 + j][cq];
      unsigned short h = f2bf(wv);
      hv[j] = h;
      lv[j] = f2bf(wv - bf2f(h));
    }
    size_t base = ((size_t)(T * 4 + ks) * 64 + lane) * 8;
    *(uint4*)&W2fh[base] = *(uint4*)hv;
    *(uint4*)&W2fl[base] = *(uint4*)lv;
  } else if (bid < 1088) {
    // ---- prep: two nodes per block, independent 128-thread halves ----
    const int sb = tid >> 7;       // half 0/1
    const int t = tid & 127;
    const int g = (bid - 576) * 2 + sb;
    const int b = g >> 6, n = g & 63;
    float* vin  = S + sb * 1152;          // 64
    float* invn = vin + 64;               // 96
    float* h0   = invn + 96;              // 128
    float* uS   = h0 + 128;               // 3
    float* rS   = uS + 3;                 // 1

    if (t == 0) {
      float px = pos[g * 3 + 0] - pos[(b * 64) * 3 + 0];
      float py = pos[g * 3 + 1] - pos[(b * 64) * 3 + 1];
      float pz = pos[g * 3 + 2] - pos[(b * 64) * 3 + 2];
      float r = sqrtf(px * px + py * py + pz * pz + 1e-12f);
      float rm = fmaxf(r, 1e-8f);
      uS[0] = px / rm; uS[1] = py / rm; uS[2] = pz / rm;
      rS[0] = r;
    }
    __syncthreads();
    const float r = rS[0];

    if (t < 32) {
      const float delta = 6.0f / 31.0f;
      const float gamma = 1.0f / (delta * delta + 1e-12f);
      int zi = z[g];
      vin[t] = z_emb[zi * 32 + t];
      float rc = fminf(r, 6.0f);
      float d = rc - (float)t * delta;
      vin[32 + t] = __expf(-gamma * d * d);
      float a = hf[g * 160 + 64 + t * 3 + 0] * uS[0]
              + hf[g * 160 + 64 + t * 3 + 1] * uS[1]
              + hf[g * 160 + 64 + t * 3 + 2] * uS[2];
      xvu[g * 32 + t] = a;
    }
    if (t < 96) {
      if (t < 64) {
        invn[t] = hf[g * 160 + t];
      } else {
        int o = t - 64;
        float v0 = hf[g * 160 + 64 + o * 3 + 0];
        float v1 = hf[g * 160 + 64 + o * 3 + 1];
        float v2 = hf[g * 160 + 64 + o * 3 + 2];
        invn[t] = sqrtf((v0 * v0 + v1 * v1 + v2 * v2) * (1.0f / 3.0f) + 1e-8f);
      }
    }
    if (t == 0) {
      float cw = 0.0f;
      if (r <= 6.0f && n != 0) cw = 0.5f * (cosf(PIF * r * (1.0f / 6.0f)) + 1.0f);
      y1cw[g * 4 + 0] = SQRT3F * uS[0];
      y1cw[g * 4 + 1] = SQRT3F * uS[1];
      y1cw[g * 4 + 2] = SQRT3F * uS[2];
      y1cw[g * 4 + 3] = cw;
    }
    __syncthreads();

    {
      float a = vwb0[t];
      #pragma unroll 8
      for (int k = 0; k < 64; ++k) a = fmaf(vin[k], vwW0[k * 128 + t], a);
      h0[t] = silu_f(a);
    }
    __syncthreads();
    {
      float a = vwb1[t];
      #pragma unroll 8
      for (int k = 0; k < 128; ++k) a = fmaf(h0[k], vwW1[k * 128 + t], a);
      float hv = silu_f(a);
      unsigned short hh = f2bf(hv);
      hTh[(size_t)g * 128 + t] = hh;
      hTl[(size_t)g * 128 + t] = f2bf(hv - bf2f(hh));
    }
    {
      float p = 0.0f;
      #pragma unroll 8
      for (int k = 0; k < 96; ++k) p = fmaf(invn[k], scW0[(96 + k) * 128 + t], p);
      #pragma unroll 8
      for (int k = 0; k < 64; ++k) p = fmaf(vin[k], scW0[(192 + k) * 128 + t], p);
      Pn[(size_t)g * 128 + t] = p;
    }
    if (n == 0) {
      float p = 0.0f;
      #pragma unroll 8
      for (int k = 0; k < 96; ++k) p = fmaf(invn[k], scW0[k * 128 + t], p);
      Pa[b * 128 + t] = p;
    }
  } else {
    // ---- smallpacks ----
    const int sb = bid - 1088;          // 0..93
    if (sb < 8) {
      pack_frag(scW1, sb * 256 + tid, W1fh, W1fl);
    } else if (sb < 30) {
      const int s = (sb - 8) * 256 + tid;
      if (s >= 5632) return;
      if (s < 1536)       pack_frag(oW0, s, O0h, O0l);
      else if (s < 3584)  pack_frag(oW1, s - 1536, O1h, O1l);
      else                pack_frag(oW2, s - 3584, O2h, O2l);
    } else {
      const int e = (sb - 30) * 2 + (tid >> 7);
      const int t = tid & 127;
      float a = scb0[t];
      #pragma unroll
      for (int k = 0; k < 16; ++k)
        a = fmaf(e_feat[e * 16 + k], scW0[(256 + k) * 128 + t], a);
      Pe[e * 128 + t] = a;
    }
  }
}

// ---------------------------------------------------------------------------
// K2 v14: MFMA GEMM + register contraction, K-SPLIT ACROSS WAVES.
// grid = 1024: cs = bid&31 (XCD-pinned, p8=cs&7=bid&7), g0=(bid>>5)*32
// (32-node M-tile). Wave w: kh=w>>1 (K half), ng=w&1 (node group of 16).
// 2x wave parallelism vs v13 (R15: grid 512 = 2 blocks/CU was the cap).
// Per-wave: 6 MFMAs/tile (2-deep chains), A-frags 16 VGPRs. tp is linear in
// K so the two K-half contraction partials sum in the LDS epilogue (LDS
// atomics into zeroed union region); bias added only by kh==0.
// ---------------------------------------------------------------------------
__device__ __forceinline__ int tile_of(int cs, int t) {
  if (t < 8)  return cs * 8 + t;
  if (t < 12) return 256 + cs * 4 + (t - 8);
  if (t < 14) return 384 + cs * 2 + (t - 12);
  return 448 + cs * 4 + (t - 14);
}

union TPSm {
  struct { unsigned short H[2][256][8]; unsigned short L[2][256][8]; } st;  // 16KB
  struct { float vals[32][160]; float sv[32][32]; } ep;                     // 24.5KB
};

__global__ void __launch_bounds__(256, 4) k_tp(
    const unsigned short* __restrict__ hTh, const unsigned short* __restrict__ hTl,
    const unsigned short* __restrict__ W2fh, const unsigned short* __restrict__ W2fl,
    const float* __restrict__ b2, const float* __restrict__ hf,
    const float* __restrict__ xvu, const float* __restrict__ y1cw,
    float* __restrict__ values8) {
  const int bid = blockIdx.x;
  const int cs = bid & 31;
  const int g0 = (bid >> 5) * 32;
  const int p8 = cs & 7;
  const int tid = threadIdx.x;
  const int w = tid >> 6, l = tid & 63;
  const int q = l >> 4, cq = l & 15;
  const int kh = w >> 1;              // K half 0/1
  const int ng = w & 1;               // node group 0/1
  const float bsc = (kh == 0) ? 1.0f : 0.0f;

  __shared__ TPSm sm;

  const int anode = g0 + ng * 16 + cq;
  v8s ah0 = *(const v8s*)&hTh[(size_t)anode * 128 + (kh * 2 + 0) * 32 + q * 8];
  v8s ah1 = *(const v8s*)&hTh[(size_t)anode * 128 + (kh * 2 + 1) * 32 + q * 8];
  v8s al0 = *(const v8s*)&hTl[(size_t)anode * 128 + (kh * 2 + 0) * 32 + q * 8];
  v8s al1 = *(const v8s*)&hTl[(size_t)anode * 128 + (kh * 2 + 1) * 32 + q * 8];

  float racc1[4][4] = {{0.f}};
  float racc2[2][4] = {{0.f}};
  float racc3[2][4][3] = {{{0.f}}};
  float racc4[4][4] = {{0.f}};

  const int nrow = ng * 16 + q * 4;

  {
    const int T = tile_of(cs, 0);
    uint4 gh = *(const uint4*)&W2fh[(size_t)T * 2048 + tid * 8];
    uint4 gl = *(const uint4*)&W2fl[(size_t)T * 2048 + tid * 8];
    *(uint4*)&sm.st.H[0][tid][0] = gh;
    *(uint4*)&sm.st.L[0][tid][0] = gl;
  }
  __syncthreads();

  #pragma unroll
  for (int t = 0; t < 18; ++t) {
    const int buf = t & 1;
    uint4 gh, gl;
    if (t < 17) {
      const int Tn = tile_of(cs, t + 1);
      gh = *(const uint4*)&W2fh[(size_t)Tn * 2048 + tid * 8];
      gl = *(const uint4*)&W2fl[(size_t)Tn * 2048 + tid * 8];
    }

    const int T = tile_of(cs, t);
    v8s bh0 = *(const v8s*)&sm.st.H[buf][(kh * 2 + 0) * 64 + l][0];
    v8s bh1 = *(const v8s*)&sm.st.H[buf][(kh * 2 + 1) * 64 + l][0];
    v8s bl0 = *(const v8s*)&sm.st.L[buf][(kh * 2 + 0) * 64 + l][0];
    v8s bl1 = *(const v8s*)&sm.st.L[buf][(kh * 2 + 1) * 64 + l][0];

    v4f a0 = (v4f){0.f, 0.f, 0.f, 0.f};
    v4f a1 = (v4f){0.f, 0.f, 0.f, 0.f};
    v4f a2 = (v4f){0.f, 0.f, 0.f, 0.f};
    a0 = __builtin_amdgcn_mfma_f32_16x16x32_bf16(ah0, bh0, a0, 0, 0, 0);
    a1 = __builtin_amdgcn_mfma_f32_16x16x32_bf16(al0, bh0, a1, 0, 0, 0);
    a2 = __builtin_amdgcn_mfma_f32_16x16x32_bf16(ah0, bl0, a2, 0, 0, 0);
    a0 = __builtin_amdgcn_mfma_f32_16x16x32_bf16(ah1, bh1, a0, 0, 0, 0);
    a1 = __builtin_amdgcn_mfma_f32_16x16x32_bf16(al1, bh1, a1, 0, 0, 0);
    a2 = __builtin_amdgcn_mfma_f32_16x16x32_bf16(ah1, bl1, a2, 0, 0, 0);
    a0 += a1; a0 += a2;
    const float bj = b2[T * 16 + cq] * bsc;
    v4f tp = a0;
    tp[0] += bj; tp[1] += bj; tp[2] += bj; tp[3] += bj;

    if (t < 8) {
      const int i = cs * 2 + (t >> 2);
      const int m = t & 3;
      #pragma unroll
      for (int r = 0; r < 4; ++r)
        racc1[m][r] = fmaf(hf[(size_t)(g0 + nrow + r) * 160 + i], tp[r], racc1[m][r]);
    } else if (t < 12) {
      const int i = cs * 2 + ((t - 8) >> 1);
      const int m = (t - 8) & 1;
      #pragma unroll
      for (int r = 0; r < 4; ++r)
        racc2[m][r] = fmaf(hf[(size_t)(g0 + nrow + r) * 160 + i], tp[r], racc2[m][r]);
    } else if (t < 14) {
      const int m = (t - 12) & 1;
      #pragma unroll
      for (int r = 0; r < 4; ++r) {
        const float* xvp = hf + (size_t)(g0 + nrow + r) * 160 + 64 + 3 * cs;
        #pragma unroll
        for (int cc = 0; cc < 3; ++cc)
          racc3[m][r][cc] = fmaf(xvp[cc], tp[r], racc3[m][r][cc]);
      }
    } else {
      const int m = (t - 14) & 3;
      #pragma unroll
      for (int r = 0; r < 4; ++r)
        racc4[m][r] = fmaf(xvu[(size_t)(g0 + nrow + r) * 32 + cs], tp[r], racc4[m][r]);
    }

    if (t < 17) {
      const int nbuf = buf ^ 1;
      *(uint4*)&sm.st.H[nbuf][tid][0] = gh;
      *(uint4*)&sm.st.L[nbuf][tid][0] = gl;
    }
    __syncthreads();
  }

  // epilogue: zero union region, then LDS atomics (2 K-halves collide 2-way)
  for (int idx = tid; idx < 6144; idx += 256) ((float*)&sm.ep)[idx] = 0.f;
  __syncthreads();

  #pragma unroll
  for (int r = 0; r < 4; ++r) {
    const int n = nrow + r;
    #pragma unroll
    for (int m = 0; m < 4; ++m)
      atomicAdd(&sm.ep.vals[n][m * 16 + cq], racc1[m][r] + racc4[m][r]);
    #pragma unroll
    for (int m = 0; m < 2; ++m)
      atomicAdd(&sm.ep.sv[n][m * 16 + cq], racc2[m][r]);
    #pragma unroll
    for (int m = 0; m < 2; ++m)
      #pragma unroll
      for (int cc = 0; cc < 3; ++cc)
        atomicAdd(&sm.ep.vals[n][64 + 3 * (m * 16 + cq) + cc], racc3[m][r][cc]);
  }
  __syncthreads();

  float* vtgt = values8 + (size_t)p8 * 163840;
  const float* y1b = y1cw + (size_t)g0 * 4;
  for (int idx = tid; idx < 5120; idx += 256) {
    int n = idx / 160, d = idx - n * 160;
    float v = sm.ep.vals[n][d];
    if (d >= 64) {
      int dd = d - 64, o = dd / 3, cc = dd - 3 * o;
      v = fmaf(sm.ep.sv[n][o], y1b[n * 4 + cc], v);
    }
    atomicAdd(&vtgt[(size_t)(g0 + n) * 160 + d], v);
  }
}

// ---------------------------------------------------------------------------
// K2b: values[n][d] = ALPHAF * sum_p values8[p][n][d]. grid=160, block=256.
// ---------------------------------------------------------------------------
__global__ void __launch_bounds__(256) k_reduce(
    const float* __restrict__ values8, float* __restrict__ values) {
  const int s = blockIdx.x * 256 + threadIdx.x;
  float4 acc = make_float4(0.f, 0.f, 0.f, 0.f);
  #pragma unroll
  for (int p = 0; p < 8; ++p) {
    float4 v = *(const float4*)&values8[(size_t)p * 163840 + s * 4];
    acc.x += v.x; acc.y += v.y; acc.z += v.z; acc.w += v.w;
  }
  acc.x *= ALPHAF; acc.y *= ALPHAF; acc.z *= ALPHAF; acc.w *= ALPHAF;
  *(float4*)&values[(size_t)s * 4] = acc;
}

// ---------------------------------------------------------------------------
// K3 v5: MFMA gate MLP + aggregation, TWO energies per block. grid=1024.
// ---------------------------------------------------------------------------
__global__ void __launch_bounds__(256, 4) k_gate_agg(
    const float* __restrict__ Pa, const float* __restrict__ Pe,
    const float* __restrict__ Pn,
    const unsigned short* __restrict__ W1fh, const unsigned short* __restrict__ W1fl,
    const float* __restrict__ b1, const float* __restrict__ W2v,
    const float* __restrict__ b2s, const float* __restrict__ y1cw,
    const float* __restrict__ values, float* __restrict__ inv_agg) {
  const int bid = blockIdx.x;
  const int b = bid >> 6;
  const int e0 = (bid & 63) * 2, e1 = e0 + 1;
  const int tid = threadIdx.x;

  __shared__ float Prow0[128], Prow1[128];
  __shared__ float gpre[2][64];
  __shared__ float gateL[2][64];
  __shared__ float aggL[2][160];
  __shared__ float normS[2];

  if (tid < 128) {
    float pa = Pa[b * 128 + tid];
    Prow0[tid] = pa + Pe[e0 * 128 + tid];
    Prow1[tid] = pa + Pe[e1 * 128 + tid];
  }
  __syncthreads();

  const int w = tid >> 6, l = tid & 63;
  const int q = l >> 4, cq = l & 15;
  const int node = w * 16 + cq;
  const float* pnrow = Pn + (size_t)(b * 64 + node) * 128;

  v4f acc0[8], acc1[8];
  #pragma unroll
  for (int t = 0; t < 8; ++t) {
    acc0[t] = (v4f){0.f, 0.f, 0.f, 0.f};
    acc1[t] = (v4f){0.f, 0.f, 0.f, 0.f};
  }

  #pragma unroll
  for (int ks = 0; ks < 4; ++ks) {
    const int k0 = ks * 32 + q * 8;
    float4 p0 = *(const float4*)(pnrow + k0);
    float4 p1 = *(const float4*)(pnrow + k0 + 4);
    float pv[8] = {p0.x, p0.y, p0.z, p0.w, p1.x, p1.y, p1.z, p1.w};
    float4 r00 = *(const float4*)(&Prow0[k0]);
    float4 r01 = *(const float4*)(&Prow0[k0 + 4]);
    float4 r10 = *(const float4*)(&Prow1[k0]);
    float4 r11 = *(const float4*)(&Prow1[k0 + 4]);
    float rv0[8] = {r00.x, r00.y, r00.z, r00.w, r01.x, r01.y, r01.z, r01.w};
    float rv1[8] = {r10.x, r10.y, r10.z, r10.w, r11.x, r11.y, r11.z, r11.w};
    v8s a0h, a0l, a1h, a1l;
    #pragma unroll
    for (int j = 0; j < 8; ++j) {
      short hs, ls;
      split_trunc(silu_f(pv[j] + rv0[j]), &hs, &ls);
      a0h[j] = hs; a0l[j] = ls;
      split_trunc(silu_f(pv[j] + rv1[j]), &hs, &ls);
      a1h[j] = hs; a1l[j] = ls;
    }
    #pragma unroll
    for (int t = 0; t < 8; ++t) {
      const size_t fb = (size_t)((ks * 8 + t) * 64 + l) * 8;
      v8s bh = *(const v8s*)&W1fh[fb];
      v8s bl = *(const v8s*)&W1fl[fb];
      acc0[t] = __builtin_amdgcn_mfma_f32_16x16x32_bf16(a0h, bh, acc0[t], 0, 0, 0);
      acc0[t] = __builtin_amdgcn_mfma_f32_16x16x32_bf16(a0l, bh, acc0[t], 0, 0, 0);
      acc0[t] = __builtin_amdgcn_mfma_f32_16x16x32_bf16(a0h, bl, acc0[t], 0, 0, 0);
      acc1[t] = __builtin_amdgcn_mfma_f32_16x16x32_bf16(a1h, bh, acc1[t], 0, 0, 0);
      acc1[t] = __builtin_amdgcn_mfma_f32_16x16x32_bf16(a1l, bh, acc1[t], 0, 0, 0);
      acc1[t] = __builtin_amdgcn_mfma_f32_16x16x32_bf16(a1h, bl, acc1[t], 0, 0, 0);
    }
  }

  float p00 = 0.f, p01 = 0.f, p02 = 0.f, p03 = 0.f;
  float p10 = 0.f, p11 = 0.f, p12 = 0.f, p13 = 0.f;
  #pragma unroll
  for (int t = 0; t < 8; ++t) {
    float bb = b1[t * 16 + cq];
    float wg = W2v[t * 16 + cq];
    p00 = fmaf(silu_f(acc0[t][0] + bb), wg, p00);
    p01 = fmaf(silu_f(acc0[t][1] + bb), wg, p01);
    p02 = fmaf(silu_f(acc0[t][2] + bb), wg, p02);
    p03 = fmaf(silu_f(acc0[t][3] + bb), wg, p03);
    p10 = fmaf(silu_f(acc1[t][0] + bb), wg, p10);
    p11 = fmaf(silu_f(acc1[t][1] + bb), wg, p11);
    p12 = fmaf(silu_f(acc1[t][2] + bb), wg, p12);
    p13 = fmaf(silu_f(acc1[t][3] + bb), wg, p13);
  }
  #pragma unroll
  for (int off = 1; off < 16; off <<= 1) {
    p00 += __shfl_xor(p00, off); p01 += __shfl_xor(p01, off);
    p02 += __shfl_xor(p02, off); p03 += __shfl_xor(p03, off);
    p10 += __shfl_xor(p10, off); p11 += __shfl_xor(p11, off);
    p12 += __shfl_xor(p12, off); p13 += __shfl_xor(p13, off);
  }
  if (cq == 0) {
    gpre[0][w * 16 + q * 4 + 0] = p00;
    gpre[0][w * 16 + q * 4 + 1] = p01;
    gpre[0][w * 16 + q * 4 + 2] = p02;
    gpre[0][w * 16 + q * 4 + 3] = p03;
    gpre[1][w * 16 + q * 4 + 0] = p10;
    gpre[1][w * 16 + q * 4 + 1] = p11;
    gpre[1][w * 16 + q * 4 + 2] = p12;
    gpre[1][w * 16 + q * 4 + 3] = p13;
  }
  __syncthreads();

  if (tid < 128) {
    const int ee = tid >> 6, ll = tid & 63;
    float gv = sigmoid_f(gpre[ee][ll] + b2s[0]);
    gv *= y1cw[(b * 64 + ll) * 4 + 3];
    gateL[ee][ll] = gv;
    float t2 = gv;
    #pragma unroll
    for (int off = 32; off > 0; off >>= 1) t2 += __shfl_down(t2, off);
    if (ll == 0) normS[ee] = fmaxf(t2, 1e-8f);
  }
  __syncthreads();

  if (tid < 160) {
    float a0 = 0.0f, a1 = 0.0f;
    const float* vp = values + (size_t)b * 64 * 160 + tid;
    #pragma unroll 4
    for (int n = 0; n < 64; ++n) {
      float v = vp[n * 160];
      a0 = fmaf(gateL[0][n], v, a0);
      a1 = fmaf(gateL[1][n], v, a1);
    }
    aggL[0][tid] = a0 / normS[0];
    aggL[1][tid] = a1 / normS[1];
  }
  __syncthreads();
  if (tid < 192) {
    const int ee = tid < 96 ? 0 : 1;
    const int ll = tid < 96 ? tid : tid - 96;
    const int e = ee == 0 ? e0 : e1;
    const float* ag = aggL[ee];
    float rv;
    if (ll < 64) {
      rv = ag[ll];
    } else {
      int o = ll - 64;
      float a0 = ag[64 + o * 3 + 0];
      float a1 = ag[64 + o * 3 + 1];
      float a2 = ag[64 + o * 3 + 2];
      rv = sqrtf((a0 * a0 + a1 * a1 + a2 * a2) * (1.0f / 3.0f) + 1e-8f);
    }
    inv_agg[(size_t)(b * 128 + e) * 96 + ll] = rv;
  }
}

// ---------------------------------------------------------------------------
// K4 v2: FUSED out-MLP (96->128 silu, 128->128 silu, 128->128) via MFMA.
// ---------------------------------------------------------------------------
__global__ void __launch_bounds__(256) k_out(
    const float* __restrict__ X,
    const unsigned short* __restrict__ O0h, const unsigned short* __restrict__ O0l,
    const unsigned short* __restrict__ O1h, const unsigned short* __restrict__ O1l,
    const unsigned short* __restrict__ O2h, const unsigned short* __restrict__ O2l,
    const float* __restrict__ b0, const float* __restrict__ b1,
    const float* __restrict__ b2, float* __restrict__ out) {
  const int r0 = blockIdx.x * 16;
  const int tid = threadIdx.x;
  const int w = tid >> 6, l = tid & 63;
  const int q = l >> 4, cq = l & 15;
  const int t0 = 2 * w, t1 = 2 * w + 1;

  __shared__ float hS[16][132];

  v4f acc0 = (v4f){0.f, 0.f, 0.f, 0.f};
  v4f acc1 = (v4f){0.f, 0.f, 0.f, 0.f};
  {
    const float* xrow = X + (size_t)(r0 + cq) * 96 + q * 8;
    #pragma unroll
    for (int ks = 0; ks < 3; ++ks) {
      float4 p0 = *(const float4*)(xrow + ks * 32);
      float4 p1 = *(const float4*)(xrow + ks * 32 + 4);
      float xv[8] = {p0.x, p0.y, p0.z, p0.w, p1.x, p1.y, p1.z, p1.w};
      v8s avh, avl;
      #pragma unroll
      for (int j = 0; j < 8; ++j) {
        short hs, ls;
        split_trunc(xv[j], &hs, &ls);
        avh[j] = hs; avl[j] = ls;
      }
      v8s b0h = *(const v8s*)&O0h[((size_t)(ks * 8 + t0) * 64 + l) * 8];
      v8s b0l = *(const v8s*)&O0l[((size_t)(ks * 8 + t0) * 64 + l) * 8];
      v8s b1h = *(const v8s*)&O0h[((size_t)(ks * 8 + t1) * 64 + l) * 8];
      v8s b1l = *(const v8s*)&O0l[((size_t)(ks * 8 + t1) * 64 + l) * 8];
      acc0 = __builtin_amdgcn_mfma_f32_16x16x32_bf16(avh, b0h, acc0, 0, 0, 0);
      acc0 = __builtin_amdgcn_mfma_f32_16x16x32_bf16(avl, b0h, acc0, 0, 0, 0);
      acc0 = __builtin_amdgcn_mfma_f32_16x16x32_bf16(avh, b0l, acc0, 0, 0, 0);
      acc1 = __builtin_amdgcn_mfma_f32_16x16x32_bf16(avh, b1h, acc1, 0, 0, 0);
      acc1 = __builtin_amdgcn_mfma_f32_16x16x32_bf16(avl, b1h, acc1, 0, 0, 0);
      acc1 = __builtin_amdgcn_mfma_f32_16x16x32_bf16(avh, b1l, acc1, 0, 0, 0);
    }
  }
  {
    const float bb0 = b0[t0 * 16 + cq], bb1 = b0[t1 * 16 + cq];
    #pragma unroll
    for (int r = 0; r < 4; ++r) {
      hS[q * 4 + r][t0 * 16 + cq] = silu_f(acc0[r] + bb0);
      hS[q * 4 + r][t1 * 16 + cq] = silu_f(acc1[r] + bb1);
    }
  }
  __syncthreads();

  v8s a2h[4], a2l[4];
  #pragma unroll
  for (int ks = 0; ks < 4; ++ks) {
    float4 p0 = *(const float4*)&hS[cq][ks * 32 + q * 8];
    float4 p1 = *(const float4*)&hS[cq][ks * 32 + q * 8 + 4];
    float xv[8] = {p0.x, p0.y, p0.z, p0.w, p1.x, p1.y, p1.z, p1.w};
    #pragma unroll
    for (int j = 0; j < 8; ++j) {
      short hs, ls;
      split_trunc(xv[j], &hs, &ls);
      a2h[ks][j] = hs; a2l[ks][j] = ls;
    }
  }
  __syncthreads();
  acc0 = (v4f){0.f, 0.f, 0.f, 0.f};
  acc1 = (v4f){0.f, 0.f, 0.f, 0.f};
  #pragma unroll
  for (int ks = 0; ks < 4; ++ks) {
    v8s b0h = *(const v8s*)&O1h[((size_t)(ks * 8 + t0) * 64 + l) * 8];
    v8s b0l = *(const v8s*)&O1l[((size_t)(ks * 8 + t0) * 64 + l) * 8];
    v8s b1h = *(const v8s*)&O1h[((size_t)(ks * 8 + t1) * 64 + l) * 8];
    v8s b1l = *(const v8s*)&O1l[((size_t)(ks * 8 + t1) * 64 + l) * 8];
    acc0 = __builtin_amdgcn_mfma_f32_16x16x32_bf16(a2h[ks], b0h, acc0, 0, 0, 0);
    acc0 = __builtin_amdgcn_mfma_f32_16x16x32_bf16(a2l[ks], b0h, acc0, 0, 0, 0);
    acc0 = __builtin_amdgcn_mfma_f32_16x16x32_bf16(a2h[ks], b0l, acc0, 0, 0, 0);
    acc1 = __builtin_amdgcn_mfma_f32_16x16x32_bf16(a2h[ks], b1h, acc1, 0, 0, 0);
    acc1 = __builtin_amdgcn_mfma_f32_16x16x32_bf16(a2l[ks], b1h, acc1, 0, 0, 0);
    acc1 = __builtin_amdgcn_mfma_f32_16x16x32_bf16(a2h[ks], b1l, acc1, 0, 0, 0);
  }
  {
    const float bb0 = b1[t0 * 16 + cq], bb1 = b1[t1 * 16 + cq];
    #pragma unroll
    for (int r = 0; r < 4; ++r) {
      hS[q * 4 + r][t0 * 16 + cq] = silu_f(acc0[r] + bb0);
      hS[q * 4 + r][t1 * 16 + cq] = silu_f(acc1[r] + bb1);
    }
  }
  __syncthreads();

  #pragma unroll
  for (int ks = 0; ks < 4; ++ks) {
    float4 p0 = *(const float4*)&hS[cq][ks * 32 + q * 8];
    float4 p1 = *(const float4*)&hS[cq][ks * 32 + q * 8 + 4];
    float xv[8] = {p0.x, p0.y, p0.z, p0.w, p1.x, p1.y, p1.z, p1.w};
    #pragma unroll
    for (int j = 0; j < 8; ++j) {
      short hs, ls;
      split_trunc(xv[j], &hs, &ls);
      a2h[ks][j] = hs; a2l[ks][j] = ls;
    }
  }
  acc0 = (v4f){0.f, 0.f, 0.f, 0.f};
  acc1 = (v4f){0.f, 0.f, 0.f, 0.f};
  #pragma unroll
  for (int ks = 0; ks < 4; ++ks) {
    v8s b0h = *(const v8s*)&O2h[((size_t)(ks * 8 + t0) * 64 + l) * 8];
    v8s b0l = *(const v8s*)&O2l[((size_t)(ks * 8 + t0) * 64 + l) * 8];
    v8s b1h = *(const v8s*)&O2h[((size_t)(ks * 8 + t1) * 64 + l) * 8];
    v8s b1l = *(const v8s*)&O2l[((size_t)(ks * 8 + t1) * 64 + l) * 8];
    acc0 = __builtin_amdgcn_mfma_f32_16x16x32_bf16(a2h[ks], b0h, acc0, 0, 0, 0);
    acc0 = __builtin_amdgcn_mfma_f32_16x16x32_bf16(a2l[ks], b0h, acc0, 0, 0, 0);
    acc0 = __builtin_amdgcn_mfma_f32_16x16x32_bf16(a2h[ks], b0l, acc0, 0, 0, 0);
    acc1 = __builtin_amdgcn_mfma_f32_16x16x32_bf16(a2h[ks], b1h, acc1, 0, 0, 0);
    acc1 = __builtin_amdgcn_mfma_f32_16x16x32_bf16(a2l[ks], b1h, acc1, 0, 0, 0);
    acc1 = __builtin_amdgcn_mfma_f32_16x16x32_bf16(a2h[ks], b1l, acc1, 0, 0, 0);
  }
  {
    const float bb0 = b2[t0 * 16 + cq], bb1 = b2[t1 * 16 + cq];
    #pragma unroll
    for (int r = 0; r < 4; ++r) {
      out[(size_t)(r0 + q * 4 + r) * 128 + t0 * 16 + cq] = acc0[r] + bb0;
      out[(size_t)(r0 + q * 4 + r) * 128 + t1 * 16 + cq] = acc1[r] + bb1;
    }
  }
}

// ---------------------------------------------------------------------------
extern "C" void kernel_launch(void* const* d_in, const int* in_sizes, int n_in,
                              void* d_out, int out_size, void* d_ws, size_t ws_size,
                              hipStream_t stream) {
  const float* hf    = (const float*)d_in[0];
  const int*   z     = (const int*)  d_in[1];
  const float* pos   = (const float*)d_in[2];
  const float* e_feat= (const float*)d_in[4];
  const float* z_emb = (const float*)d_in[5];
  const float* vwW0  = (const float*)d_in[6];
  const float* vwb0  = (const float*)d_in[7];
  const float* vwW1  = (const float*)d_in[8];
  const float* vwb1  = (const float*)d_in[9];
  const float* vwW2  = (const float*)d_in[10];
  const float* vwb2  = (const float*)d_in[11];
  const float* scW0  = (const float*)d_in[12];
  const float* scb0  = (const float*)d_in[13];
  const float* scW1  = (const float*)d_in[14];
  const float* scb1  = (const float*)d_in[15];
  const float* scW2  = (const float*)d_in[16];
  const float* scb2  = (const float*)d_in[17];
  const float* oW0   = (const float*)d_in[18];
  const float* ob0   = (const float*)d_in[19];
  const float* oW1   = (const float*)d_in[20];
  const float* ob1   = (const float*)d_in[21];
  const float* oW2   = (const float*)d_in[22];
  const float* ob2   = (const float*)d_in[23];
  float* out = (float*)d_out;

  float* ws = (float*)d_ws;
  unsigned short* W2fh = (unsigned short*)(ws);            // 589824 fl
  unsigned short* W2fl = (unsigned short*)(ws + 589824);   // 589824 fl
  unsigned short* hTh  = (unsigned short*)(ws + 1179648);  // 65536 fl
  unsigned short* hTl  = (unsigned short*)(ws + 1245184);  // 65536 fl
  float* Pn     = ws + 1310720;   // 131072
  float* Pa     = Pn + 131072;    // 2048
  float* Pe     = Pa + 2048;      // 16384
  float* xvu    = Pe + 16384;     // 32768
  float* y1cw   = xvu + 32768;    // 4096
  float* values = y1cw + 4096;    // 163840
  float* invagg = values + 163840;// 196608
  unsigned short* W1fh = (unsigned short*)(invagg + 196608);  // 8192 fl
  unsigned short* W1fl = (unsigned short*)(invagg + 196608 + 8192);
  float* values8 = invagg + 196608 + 16384;  // 8*163840 fl
  unsigned short* Ob = (unsigned short*)(values8 + 8 * 163840);
  unsigned short* O0h = Ob;
  unsigned short* O0l = Ob + 12288;
  unsigned short* O1h = Ob + 24576;
  unsigned short* O1l = Ob + 40960;
  unsigned short* O2h = Ob + 57344;
  unsigned short* O2l = Ob + 73728;

  hipMemsetAsync(values8, 0, 8 * 163840 * sizeof(float), stream);

  k_front<<<1182, 256, 0, stream>>>(
      vwW2, W2fh, W2fl,
      hf, z, pos, z_emb, vwW0, vwb0, vwW1, vwb1, scW0,
      hTh, hTl, Pn, Pa, xvu, y1cw,
      scW1, W1fh, W1fl, oW0, oW1, oW2,
      O0h, O0l, O1h, O1l, O2h, O2l,
      e_feat, scb0, Pe);
  k_tp<<<1024, 256, 0, stream>>>(hTh, hTl, W2fh, W2fl, vwb2, hf, xvu,
                                 y1cw, values8);
  k_reduce<<<160, 256, 0, stream>>>(values8, values);
  k_gate_agg<<<1024, 256, 0, stream>>>(Pa, Pe, Pn, W1fh, W1fl, scb1, scW2, scb2,
                                       y1cw, values, invagg);
  k_out<<<128, 256, 0, stream>>>(invagg, O0h, O0l, O1h, O1l, O2h, O2l,
                                 ob0, ob1, ob2, out);
}

// Round 17
// 205.478 us; speedup vs baseline: 1.3180x; 1.3180x over previous
//
#include <hip/hip_runtime.h>
#include <hip/hip_bf16.h>
#include <math.h>

// Sizes: B=16, N=64, nE=128, H=128, LAT=128, NS=64, NV=32, INV=96, D_NODE=160
#define SQRT3F 1.7320508075688772f
#define ALPHAF 0.10206207261596577f  // 1/sqrt(96)
#define PIF 3.14159265358979323846f

typedef short v8s __attribute__((ext_vector_type(8)));
typedef float v4f __attribute__((ext_vector_type(4)));

__device__ __forceinline__ float silu_f(float x) {
  return x / (1.0f + __expf(-x));
}
__device__ __forceinline__ float sigmoid_f(float x) {
  return 1.0f / (1.0f + __expf(-x));
}
__device__ __forceinline__ unsigned short f2bf(float f) {
  unsigned int u = __float_as_uint(f);
  unsigned int r = (u + 0x7fffu + ((u >> 16) & 1u)) >> 16;
  return (unsigned short)r;
}
__device__ __forceinline__ float bf2f(unsigned short h) {
  return __uint_as_float(((unsigned int)h) << 16);
}
__device__ __forceinline__ void split_trunc(float x, short* h, short* l) {
  unsigned int u = __float_as_uint(x);
  unsigned short hs = (unsigned short)(u >> 16);
  float r = x - __uint_as_float((unsigned int)hs << 16);
  *h = (short)hs;
  *l = (short)(__float_as_uint(r) >> 16);
}

__device__ __forceinline__ void pack_frag(const float* __restrict__ W, int s0,
                                          unsigned short* __restrict__ fh,
                                          unsigned short* __restrict__ fl) {
  const int lane = s0 & 63;
  const int t = (s0 >> 6) & 7;
  const int ks = s0 >> 9;
  const int kbase = ks * 32 + (lane >> 4) * 8;
  const int n = t * 16 + (lane & 15);
  unsigned short hv[8], lv[8];
  #pragma unroll
  for (int j = 0; j < 8; ++j) {
    float w = W[(size_t)(kbase + j) * 128 + n];
    unsigned short h = f2bf(w);
    hv[j] = h;
    lv[j] = f2bf(w - bf2f(h));
  }
  *(uint4*)&fh[(size_t)s0 * 8] = *(uint4*)hv;
  *(uint4*)&fl[(size_t)s0 * 8] = *(uint4*)lv;
}

// ---------------------------------------------------------------------------
// K_FRONT: merged castw2 (blocks 0..575) + prep (576..1087, 2 nodes/block)
// + castw1/packout/Pe (1088..1181). (kept from R16 — saved ~10us)
// ---------------------------------------------------------------------------
__global__ void __launch_bounds__(256) k_front(
    const float* __restrict__ W2, unsigned short* __restrict__ W2fh,
    unsigned short* __restrict__ W2fl,
    const float* __restrict__ hf, const int* __restrict__ z,
    const float* __restrict__ pos, const float* __restrict__ z_emb,
    const float* __restrict__ vwW0, const float* __restrict__ vwb0,
    const float* __restrict__ vwW1, const float* __restrict__ vwb1,
    const float* __restrict__ scW0,
    unsigned short* __restrict__ hTh, unsigned short* __restrict__ hTl,
    float* __restrict__ Pn, float* __restrict__ Pa,
    float* __restrict__ xvu, float* __restrict__ y1cw,
    const float* __restrict__ scW1,
    unsigned short* __restrict__ W1fh, unsigned short* __restrict__ W1fl,
    const float* __restrict__ oW0, const float* __restrict__ oW1,
    const float* __restrict__ oW2,
    unsigned short* __restrict__ O0h, unsigned short* __restrict__ O0l,
    unsigned short* __restrict__ O1h, unsigned short* __restrict__ O1l,
    unsigned short* __restrict__ O2h, unsigned short* __restrict__ O2l,
    const float* __restrict__ e_feat, const float* __restrict__ scb0,
    float* __restrict__ Pe) {
  const int bid = blockIdx.x;
  const int tid = threadIdx.x;
  __shared__ float S[2304];

  if (bid < 576) {
    const int T = bid;
    float (*Tl)[17] = (float(*)[17])S;
    for (int idx = tid; idx < 2048; idx += 256) {
      int k = idx >> 4, cc = idx & 15;
      Tl[k][cc] = W2[(size_t)k * 9216 + T * 16 + cc];
    }
    __syncthreads();
    const int ks = tid >> 6, lane = tid & 63;
    const int q = lane >> 4, cq = lane & 15;
    const int k0 = ks * 32 + q * 8;
    unsigned short hv[8], lv[8];
    #pragma unroll
    for (int j = 0; j < 8; ++j) {
      float wv = Tl[k0 + j][cq];
      unsigned short h = f2bf(wv);
      hv[j] = h;
      lv[j] = f2bf(wv - bf2f(h));
    }
    size_t base = ((size_t)(T * 4 + ks) * 64 + lane) * 8;
    *(uint4*)&W2fh[base] = *(uint4*)hv;
    *(uint4*)&W2fl[base] = *(uint4*)lv;
  } else if (bid < 1088) {
    const int sb = tid >> 7;
    const int t = tid & 127;
    const int g = (bid - 576) * 2 + sb;
    const int b = g >> 6, n = g & 63;
    float* vin  = S + sb * 1152;
    float* invn = vin + 64;
    float* h0   = invn + 96;
    float* uS   = h0 + 128;
    float* rS   = uS + 3;

    if (t == 0) {
      float px = pos[g * 3 + 0] - pos[(b * 64) * 3 + 0];
      float py = pos[g * 3 + 1] - pos[(b * 64) * 3 + 1];
      float pz = pos[g * 3 + 2] - pos[(b * 64) * 3 + 2];
      float r = sqrtf(px * px + py * py + pz * pz + 1e-12f);
      float rm = fmaxf(r, 1e-8f);
      uS[0] = px / rm; uS[1] = py / rm; uS[2] = pz / rm;
      rS[0] = r;
    }
    __syncthreads();
    const float r = rS[0];

    if (t < 32) {
      const float delta = 6.0f / 31.0f;
      const float gamma = 1.0f / (delta * delta + 1e-12f);
      int zi = z[g];
      vin[t] = z_emb[zi * 32 + t];
      float rc = fminf(r, 6.0f);
      float d = rc - (float)t * delta;
      vin[32 + t] = __expf(-gamma * d * d);
      float a = hf[g * 160 + 64 + t * 3 + 0] * uS[0]
              + hf[g * 160 + 64 + t * 3 + 1] * uS[1]
              + hf[g * 160 + 64 + t * 3 + 2] * uS[2];
      xvu[g * 32 + t] = a;
    }
    if (t < 96) {
      if (t < 64) {
        invn[t] = hf[g * 160 + t];
      } else {
        int o = t - 64;
        float v0 = hf[g * 160 + 64 + o * 3 + 0];
        float v1 = hf[g * 160 + 64 + o * 3 + 1];
        float v2 = hf[g * 160 + 64 + o * 3 + 2];
        invn[t] = sqrtf((v0 * v0 + v1 * v1 + v2 * v2) * (1.0f / 3.0f) + 1e-8f);
      }
    }
    if (t == 0) {
      float cw = 0.0f;
      if (r <= 6.0f && n != 0) cw = 0.5f * (cosf(PIF * r * (1.0f / 6.0f)) + 1.0f);
      y1cw[g * 4 + 0] = SQRT3F * uS[0];
      y1cw[g * 4 + 1] = SQRT3F * uS[1];
      y1cw[g * 4 + 2] = SQRT3F * uS[2];
      y1cw[g * 4 + 3] = cw;
    }
    __syncthreads();

    {
      float a = vwb0[t];
      #pragma unroll 8
      for (int k = 0; k < 64; ++k) a = fmaf(vin[k], vwW0[k * 128 + t], a);
      h0[t] = silu_f(a);
    }
    __syncthreads();
    {
      float a = vwb1[t];
      #pragma unroll 8
      for (int k = 0; k < 128; ++k) a = fmaf(h0[k], vwW1[k * 128 + t], a);
      float hv = silu_f(a);
      unsigned short hh = f2bf(hv);
      hTh[(size_t)g * 128 + t] = hh;
      hTl[(size_t)g * 128 + t] = f2bf(hv - bf2f(hh));
    }
    {
      float p = 0.0f;
      #pragma unroll 8
      for (int k = 0; k < 96; ++k) p = fmaf(invn[k], scW0[(96 + k) * 128 + t], p);
      #pragma unroll 8
      for (int k = 0; k < 64; ++k) p = fmaf(vin[k], scW0[(192 + k) * 128 + t], p);
      Pn[(size_t)g * 128 + t] = p;
    }
    if (n == 0) {
      float p = 0.0f;
      #pragma unroll 8
      for (int k = 0; k < 96; ++k) p = fmaf(invn[k], scW0[k * 128 + t], p);
      Pa[b * 128 + t] = p;
    }
  } else {
    const int sb = bid - 1088;
    if (sb < 8) {
      pack_frag(scW1, sb * 256 + tid, W1fh, W1fl);
    } else if (sb < 30) {
      const int s = (sb - 8) * 256 + tid;
      if (s >= 5632) return;
      if (s < 1536)       pack_frag(oW0, s, O0h, O0l);
      else if (s < 3584)  pack_frag(oW1, s - 1536, O1h, O1l);
      else                pack_frag(oW2, s - 3584, O2h, O2l);
    } else {
      const int e = (sb - 30) * 2 + (tid >> 7);
      const int t = tid & 127;
      float a = scb0[t];
      #pragma unroll
      for (int k = 0; k < 16; ++k)
        a = fmaf(e_feat[e * 16 + k], scW0[(256 + k) * 128 + t], a);
      Pe[e * 128 + t] = a;
    }
  }
}

// ---------------------------------------------------------------------------
// K2 v12 (REVERT — measured best <=41us): MFMA GEMM + register contraction,
// canonical LDS-B pipeline. grid=512: cs=bid&31 (XCD-pinned p8=cs&7),
// g0=(bid>>5)*64 (64-node M-tile, 4 waves x 16 nodes). 18 tiles/block,
// 12 MFMA/wave/tile. R16 lesson: halving per-block work while keeping the
// 18-stage barrier chain doubles total time — the loop is staging-bound per
// block, so maximize MFMA per staging round.
// ---------------------------------------------------------------------------
__device__ __forceinline__ int tile_of(int cs, int t) {
  if (t < 8)  return cs * 8 + t;
  if (t < 12) return 256 + cs * 4 + (t - 8);
  if (t < 14) return 384 + cs * 2 + (t - 12);
  return 448 + cs * 4 + (t - 14);
}

__global__ void __launch_bounds__(256) k_tp(
    const unsigned short* __restrict__ hTh, const unsigned short* __restrict__ hTl,
    const unsigned short* __restrict__ W2fh, const unsigned short* __restrict__ W2fl,
    const float* __restrict__ b2, const float* __restrict__ hf,
    const float* __restrict__ xvu, const float* __restrict__ y1cw,
    float* __restrict__ values8) {
  const int bid = blockIdx.x;
  const int cs = bid & 31;
  const int g0 = (bid >> 5) * 64;
  const int p8 = cs & 7;
  const int tid = threadIdx.x;
  const int w = tid >> 6, l = tid & 63;
  const int q = l >> 4, cq = l & 15;

  __shared__ unsigned short BstH[2][256][8];
  __shared__ unsigned short BstL[2][256][8];
  __shared__ float valsS[64][160];
  __shared__ float svS[64][32];

  const int anode = g0 + w * 16 + cq;
  v8s ah0 = *(const v8s*)&hTh[(size_t)anode * 128 + 0 * 32 + q * 8];
  v8s ah1 = *(const v8s*)&hTh[(size_t)anode * 128 + 1 * 32 + q * 8];
  v8s ah2 = *(const v8s*)&hTh[(size_t)anode * 128 + 2 * 32 + q * 8];
  v8s ah3 = *(const v8s*)&hTh[(size_t)anode * 128 + 3 * 32 + q * 8];
  v8s al0 = *(const v8s*)&hTl[(size_t)anode * 128 + 0 * 32 + q * 8];
  v8s al1 = *(const v8s*)&hTl[(size_t)anode * 128 + 1 * 32 + q * 8];
  v8s al2 = *(const v8s*)&hTl[(size_t)anode * 128 + 2 * 32 + q * 8];
  v8s al3 = *(const v8s*)&hTl[(size_t)anode * 128 + 3 * 32 + q * 8];

  float racc1[4][4] = {{0.f}};
  float racc2[2][4] = {{0.f}};
  float racc3[2][4][3] = {{{0.f}}};
  float racc4[4][4] = {{0.f}};

  const int nrow = w * 16 + q * 4;

  {
    const int T = tile_of(cs, 0);
    uint4 gh = *(const uint4*)&W2fh[(size_t)T * 2048 + tid * 8];
    uint4 gl = *(const uint4*)&W2fl[(size_t)T * 2048 + tid * 8];
    *(uint4*)&BstH[0][tid][0] = gh;
    *(uint4*)&BstL[0][tid][0] = gl;
  }
  __syncthreads();

  #pragma unroll
  for (int t = 0; t < 18; ++t) {
    const int buf = t & 1;
    uint4 gh, gl;
    if (t < 17) {
      const int Tn = tile_of(cs, t + 1);
      gh = *(const uint4*)&W2fh[(size_t)Tn * 2048 + tid * 8];
      gl = *(const uint4*)&W2fl[(size_t)Tn * 2048 + tid * 8];
    }

    const int T = tile_of(cs, t);
    v8s bh0 = *(const v8s*)&BstH[buf][0 * 64 + l][0];
    v8s bh1 = *(const v8s*)&BstH[buf][1 * 64 + l][0];
    v8s bh2 = *(const v8s*)&BstH[buf][2 * 64 + l][0];
    v8s bh3 = *(const v8s*)&BstH[buf][3 * 64 + l][0];
    v8s bl0 = *(const v8s*)&BstL[buf][0 * 64 + l][0];
    v8s bl1 = *(const v8s*)&BstL[buf][1 * 64 + l][0];
    v8s bl2 = *(const v8s*)&BstL[buf][2 * 64 + l][0];
    v8s bl3 = *(const v8s*)&BstL[buf][3 * 64 + l][0];

    v4f a0 = (v4f){0.f, 0.f, 0.f, 0.f};
    v4f a1 = (v4f){0.f, 0.f, 0.f, 0.f};
    v4f a2 = (v4f){0.f, 0.f, 0.f, 0.f};
    a0 = __builtin_amdgcn_mfma_f32_16x16x32_bf16(ah0, bh0, a0, 0, 0, 0);
    a1 = __builtin_amdgcn_mfma_f32_16x16x32_bf16(al0, bh0, a1, 0, 0, 0);
    a2 = __builtin_amdgcn_mfma_f32_16x16x32_bf16(ah0, bl0, a2, 0, 0, 0);
    a0 = __builtin_amdgcn_mfma_f32_16x16x32_bf16(ah1, bh1, a0, 0, 0, 0);
    a1 = __builtin_amdgcn_mfma_f32_16x16x32_bf16(al1, bh1, a1, 0, 0, 0);
    a2 = __builtin_amdgcn_mfma_f32_16x16x32_bf16(ah1, bl1, a2, 0, 0, 0);
    a0 = __builtin_amdgcn_mfma_f32_16x16x32_bf16(ah2, bh2, a0, 0, 0, 0);
    a1 = __builtin_amdgcn_mfma_f32_16x16x32_bf16(al2, bh2, a1, 0, 0, 0);
    a2 = __builtin_amdgcn_mfma_f32_16x16x32_bf16(ah2, bl2, a2, 0, 0, 0);
    a0 = __builtin_amdgcn_mfma_f32_16x16x32_bf16(ah3, bh3, a0, 0, 0, 0);
    a1 = __builtin_amdgcn_mfma_f32_16x16x32_bf16(al3, bh3, a1, 0, 0, 0);
    a2 = __builtin_amdgcn_mfma_f32_16x16x32_bf16(ah3, bl3, a2, 0, 0, 0);
    a0 += a1; a0 += a2;
    const float bj = b2[T * 16 + cq];
    v4f tp = a0;
    tp[0] += bj; tp[1] += bj; tp[2] += bj; tp[3] += bj;

    if (t < 8) {
      const int i = cs * 2 + (t >> 2);
      const int m = t & 3;
      #pragma unroll
      for (int r = 0; r < 4; ++r)
        racc1[m][r] = fmaf(hf[(size_t)(g0 + nrow + r) * 160 + i], tp[r], racc1[m][r]);
    } else if (t < 12) {
      const int i = cs * 2 + ((t - 8) >> 1);
      const int m = (t - 8) & 1;
      #pragma unroll
      for (int r = 0; r < 4; ++r)
        racc2[m][r] = fmaf(hf[(size_t)(g0 + nrow + r) * 160 + i], tp[r], racc2[m][r]);
    } else if (t < 14) {
      const int m = (t - 12) & 1;
      #pragma unroll
      for (int r = 0; r < 4; ++r) {
        const float* xvp = hf + (size_t)(g0 + nrow + r) * 160 + 64 + 3 * cs;
        #pragma unroll
        for (int cc = 0; cc < 3; ++cc)
          racc3[m][r][cc] = fmaf(xvp[cc], tp[r], racc3[m][r][cc]);
      }
    } else {
      const int m = (t - 14) & 3;
      #pragma unroll
      for (int r = 0; r < 4; ++r)
        racc4[m][r] = fmaf(xvu[(size_t)(g0 + nrow + r) * 32 + cs], tp[r], racc4[m][r]);
    }

    if (t < 17) {
      const int nbuf = buf ^ 1;
      *(uint4*)&BstH[nbuf][tid][0] = gh;
      *(uint4*)&BstL[nbuf][tid][0] = gl;
    }
    __syncthreads();
  }

  // epilogue: owner-exclusive plain stores
  #pragma unroll
  for (int r = 0; r < 4; ++r) {
    const int n = nrow + r;
    #pragma unroll
    for (int m = 0; m < 4; ++m)
      valsS[n][m * 16 + cq] = racc1[m][r] + racc4[m][r];
    #pragma unroll
    for (int m = 0; m < 2; ++m)
      svS[n][m * 16 + cq] = racc2[m][r];
    #pragma unroll
    for (int m = 0; m < 2; ++m)
      #pragma unroll
      for (int cc = 0; cc < 3; ++cc)
        valsS[n][64 + 3 * (m * 16 + cq) + cc] = racc3[m][r][cc];
  }
  __syncthreads();

  float* vtgt = values8 + (size_t)p8 * 163840;
  const float* y1b = y1cw + (size_t)g0 * 4;
  for (int idx = tid; idx < 10240; idx += 256) {
    int n = idx / 160, d = idx - n * 160;
    float v = valsS[n][d];
    if (d >= 64) {
      int dd = d - 64, o = dd / 3, cc = dd - 3 * o;
      v = fmaf(svS[n][o], y1b[n * 4 + cc], v);
    }
    atomicAdd(&vtgt[(size_t)(g0 + n) * 160 + d], v);
  }
}

// ---------------------------------------------------------------------------
// K2b: values[n][d] = ALPHAF * sum_p values8[p][n][d]. grid=160, block=256.
// ---------------------------------------------------------------------------
__global__ void __launch_bounds__(256) k_reduce(
    const float* __restrict__ values8, float* __restrict__ values) {
  const int s = blockIdx.x * 256 + threadIdx.x;
  float4 acc = make_float4(0.f, 0.f, 0.f, 0.f);
  #pragma unroll
  for (int p = 0; p < 8; ++p) {
    float4 v = *(const float4*)&values8[(size_t)p * 163840 + s * 4];
    acc.x += v.x; acc.y += v.y; acc.z += v.z; acc.w += v.w;
  }
  acc.x *= ALPHAF; acc.y *= ALPHAF; acc.z *= ALPHAF; acc.w *= ALPHAF;
  *(float4*)&values[(size_t)s * 4] = acc;
}

// ---------------------------------------------------------------------------
// K3 v5: MFMA gate MLP + aggregation, TWO energies per block. grid=1024.
// ---------------------------------------------------------------------------
__global__ void __launch_bounds__(256, 4) k_gate_agg(
    const float* __restrict__ Pa, const float* __restrict__ Pe,
    const float* __restrict__ Pn,
    const unsigned short* __restrict__ W1fh, const unsigned short* __restrict__ W1fl,
    const float* __restrict__ b1, const float* __restrict__ W2v,
    const float* __restrict__ b2s, const float* __restrict__ y1cw,
    const float* __restrict__ values, float* __restrict__ inv_agg) {
  const int bid = blockIdx.x;
  const int b = bid >> 6;
  const int e0 = (bid & 63) * 2, e1 = e0 + 1;
  const int tid = threadIdx.x;

  __shared__ float Prow0[128], Prow1[128];
  __shared__ float gpre[2][64];
  __shared__ float gateL[2][64];
  __shared__ float aggL[2][160];
  __shared__ float normS[2];

  if (tid < 128) {
    float pa = Pa[b * 128 + tid];
    Prow0[tid] = pa + Pe[e0 * 128 + tid];
    Prow1[tid] = pa + Pe[e1 * 128 + tid];
  }
  __syncthreads();

  const int w = tid >> 6, l = tid & 63;
  const int q = l >> 4, cq = l & 15;
  const int node = w * 16 + cq;
  const float* pnrow = Pn + (size_t)(b * 64 + node) * 128;

  v4f acc0[8], acc1[8];
  #pragma unroll
  for (int t = 0; t < 8; ++t) {
    acc0[t] = (v4f){0.f, 0.f, 0.f, 0.f};
    acc1[t] = (v4f){0.f, 0.f, 0.f, 0.f};
  }

  #pragma unroll
  for (int ks = 0; ks < 4; ++ks) {
    const int k0 = ks * 32 + q * 8;
    float4 p0 = *(const float4*)(pnrow + k0);
    float4 p1 = *(const float4*)(pnrow + k0 + 4);
    float pv[8] = {p0.x, p0.y, p0.z, p0.w, p1.x, p1.y, p1.z, p1.w};
    float4 r00 = *(const float4*)(&Prow0[k0]);
    float4 r01 = *(const float4*)(&Prow0[k0 + 4]);
    float4 r10 = *(const float4*)(&Prow1[k0]);
    float4 r11 = *(const float4*)(&Prow1[k0 + 4]);
    float rv0[8] = {r00.x, r00.y, r00.z, r00.w, r01.x, r01.y, r01.z, r01.w};
    float rv1[8] = {r10.x, r10.y, r10.z, r10.w, r11.x, r11.y, r11.z, r11.w};
    v8s a0h, a0l, a1h, a1l;
    #pragma unroll
    for (int j = 0; j < 8; ++j) {
      short hs, ls;
      split_trunc(silu_f(pv[j] + rv0[j]), &hs, &ls);
      a0h[j] = hs; a0l[j] = ls;
      split_trunc(silu_f(pv[j] + rv1[j]), &hs, &ls);
      a1h[j] = hs; a1l[j] = ls;
    }
    #pragma unroll
    for (int t = 0; t < 8; ++t) {
      const size_t fb = (size_t)((ks * 8 + t) * 64 + l) * 8;
      v8s bh = *(const v8s*)&W1fh[fb];
      v8s bl = *(const v8s*)&W1fl[fb];
      acc0[t] = __builtin_amdgcn_mfma_f32_16x16x32_bf16(a0h, bh, acc0[t], 0, 0, 0);
      acc0[t] = __builtin_amdgcn_mfma_f32_16x16x32_bf16(a0l, bh, acc0[t], 0, 0, 0);
      acc0[t] = __builtin_amdgcn_mfma_f32_16x16x32_bf16(a0h, bl, acc0[t], 0, 0, 0);
      acc1[t] = __builtin_amdgcn_mfma_f32_16x16x32_bf16(a1h, bh, acc1[t], 0, 0, 0);
      acc1[t] = __builtin_amdgcn_mfma_f32_16x16x32_bf16(a1l, bh, acc1[t], 0, 0, 0);
      acc1[t] = __builtin_amdgcn_mfma_f32_16x16x32_bf16(a1h, bl, acc1[t], 0, 0, 0);
    }
  }

  float p00 = 0.f, p01 = 0.f, p02 = 0.f, p03 = 0.f;
  float p10 = 0.f, p11 = 0.f, p12 = 0.f, p13 = 0.f;
  #pragma unroll
  for (int t = 0; t < 8; ++t) {
    float bb = b1[t * 16 + cq];
    float wg = W2v[t * 16 + cq];
    p00 = fmaf(silu_f(acc0[t][0] + bb), wg, p00);
    p01 = fmaf(silu_f(acc0[t][1] + bb), wg, p01);
    p02 = fmaf(silu_f(acc0[t][2] + bb), wg, p02);
    p03 = fmaf(silu_f(acc0[t][3] + bb), wg, p03);
    p10 = fmaf(silu_f(acc1[t][0] + bb), wg, p10);
    p11 = fmaf(silu_f(acc1[t][1] + bb), wg, p11);
    p12 = fmaf(silu_f(acc1[t][2] + bb), wg, p12);
    p13 = fmaf(silu_f(acc1[t][3] + bb), wg, p13);
  }
  #pragma unroll
  for (int off = 1; off < 16; off <<= 1) {
    p00 += __shfl_xor(p00, off); p01 += __shfl_xor(p01, off);
    p02 += __shfl_xor(p02, off); p03 += __shfl_xor(p03, off);
    p10 += __shfl_xor(p10, off); p11 += __shfl_xor(p11, off);
    p12 += __shfl_xor(p12, off); p13 += __shfl_xor(p13, off);
  }
  if (cq == 0) {
    gpre[0][w * 16 + q * 4 + 0] = p00;
    gpre[0][w * 16 + q * 4 + 1] = p01;
    gpre[0][w * 16 + q * 4 + 2] = p02;
    gpre[0][w * 16 + q * 4 + 3] = p03;
    gpre[1][w * 16 + q * 4 + 0] = p10;
    gpre[1][w * 16 + q * 4 + 1] = p11;
    gpre[1][w * 16 + q * 4 + 2] = p12;
    gpre[1][w * 16 + q * 4 + 3] = p13;
  }
  __syncthreads();

  if (tid < 128) {
    const int ee = tid >> 6, ll = tid & 63;
    float gv = sigmoid_f(gpre[ee][ll] + b2s[0]);
    gv *= y1cw[(b * 64 + ll) * 4 + 3];
    gateL[ee][ll] = gv;
    float t2 = gv;
    #pragma unroll
    for (int off = 32; off > 0; off >>= 1) t2 += __shfl_down(t2, off);
    if (ll == 0) normS[ee] = fmaxf(t2, 1e-8f);
  }
  __syncthreads();

  if (tid < 160) {
    float a0 = 0.0f, a1 = 0.0f;
    const float* vp = values + (size_t)b * 64 * 160 + tid;
    #pragma unroll 4
    for (int n = 0; n < 64; ++n) {
      float v = vp[n * 160];
      a0 = fmaf(gateL[0][n], v, a0);
      a1 = fmaf(gateL[1][n], v, a1);
    }
    aggL[0][tid] = a0 / normS[0];
    aggL[1][tid] = a1 / normS[1];
  }
  __syncthreads();
  if (tid < 192) {
    const int ee = tid < 96 ? 0 : 1;
    const int ll = tid < 96 ? tid : tid - 96;
    const int e = ee == 0 ? e0 : e1;
    const float* ag = aggL[ee];
    float rv;
    if (ll < 64) {
      rv = ag[ll];
    } else {
      int o = ll - 64;
      float a0 = ag[64 + o * 3 + 0];
      float a1 = ag[64 + o * 3 + 1];
      float a2 = ag[64 + o * 3 + 2];
      rv = sqrtf((a0 * a0 + a1 * a1 + a2 * a2) * (1.0f / 3.0f) + 1e-8f);
    }
    inv_agg[(size_t)(b * 128 + e) * 96 + ll] = rv;
  }
}

// ---------------------------------------------------------------------------
// K4 v2: FUSED out-MLP (96->128 silu, 128->128 silu, 128->128) via MFMA.
// ---------------------------------------------------------------------------
__global__ void __launch_bounds__(256) k_out(
    const float* __restrict__ X,
    const unsigned short* __restrict__ O0h, const unsigned short* __restrict__ O0l,
    const unsigned short* __restrict__ O1h, const unsigned short* __restrict__ O1l,
    const unsigned short* __restrict__ O2h, const unsigned short* __restrict__ O2l,
    const float* __restrict__ b0, const float* __restrict__ b1,
    const float* __restrict__ b2, float* __restrict__ out) {
  const int r0 = blockIdx.x * 16;
  const int tid = threadIdx.x;
  const int w = tid >> 6, l = tid & 63;
  const int q = l >> 4, cq = l & 15;
  const int t0 = 2 * w, t1 = 2 * w + 1;

  __shared__ float hS[16][132];

  v4f acc0 = (v4f){0.f, 0.f, 0.f, 0.f};
  v4f acc1 = (v4f){0.f, 0.f, 0.f, 0.f};
  {
    const float* xrow = X + (size_t)(r0 + cq) * 96 + q * 8;
    #pragma unroll
    for (int ks = 0; ks < 3; ++ks) {
      float4 p0 = *(const float4*)(xrow + ks * 32);
      float4 p1 = *(const float4*)(xrow + ks * 32 + 4);
      float xv[8] = {p0.x, p0.y, p0.z, p0.w, p1.x, p1.y, p1.z, p1.w};
      v8s avh, avl;
      #pragma unroll
      for (int j = 0; j < 8; ++j) {
        short hs, ls;
        split_trunc(xv[j], &hs, &ls);
        avh[j] = hs; avl[j] = ls;
      }
      v8s b0h = *(const v8s*)&O0h[((size_t)(ks * 8 + t0) * 64 + l) * 8];
      v8s b0l = *(const v8s*)&O0l[((size_t)(ks * 8 + t0) * 64 + l) * 8];
      v8s b1h = *(const v8s*)&O0h[((size_t)(ks * 8 + t1) * 64 + l) * 8];
      v8s b1l = *(const v8s*)&O0l[((size_t)(ks * 8 + t1) * 64 + l) * 8];
      acc0 = __builtin_amdgcn_mfma_f32_16x16x32_bf16(avh, b0h, acc0, 0, 0, 0);
      acc0 = __builtin_amdgcn_mfma_f32_16x16x32_bf16(avl, b0h, acc0, 0, 0, 0);
      acc0 = __builtin_amdgcn_mfma_f32_16x16x32_bf16(avh, b0l, acc0, 0, 0, 0);
      acc1 = __builtin_amdgcn_mfma_f32_16x16x32_bf16(avh, b1h, acc1, 0, 0, 0);
      acc1 = __builtin_amdgcn_mfma_f32_16x16x32_bf16(avl, b1h, acc1, 0, 0, 0);
      acc1 = __builtin_amdgcn_mfma_f32_16x16x32_bf16(avh, b1l, acc1, 0, 0, 0);
    }
  }
  {
    const float bb0 = b0[t0 * 16 + cq], bb1 = b0[t1 * 16 + cq];
    #pragma unroll
    for (int r = 0; r < 4; ++r) {
      hS[q * 4 + r][t0 * 16 + cq] = silu_f(acc0[r] + bb0);
      hS[q * 4 + r][t1 * 16 + cq] = silu_f(acc1[r] + bb1);
    }
  }
  __syncthreads();

  v8s a2h[4], a2l[4];
  #pragma unroll
  for (int ks = 0; ks < 4; ++ks) {
    float4 p0 = *(const float4*)&hS[cq][ks * 32 + q * 8];
    float4 p1 = *(const float4*)&hS[cq][ks * 32 + q * 8 + 4];
    float xv[8] = {p0.x, p0.y, p0.z, p0.w, p1.x, p1.y, p1.z, p1.w};
    #pragma unroll
    for (int j = 0; j < 8; ++j) {
      short hs, ls;
      split_trunc(xv[j], &hs, &ls);
      a2h[ks][j] = hs; a2l[ks][j] = ls;
    }
  }
  __syncthreads();
  acc0 = (v4f){0.f, 0.f, 0.f, 0.f};
  acc1 = (v4f){0.f, 0.f, 0.f, 0.f};
  #pragma unroll
  for (int ks = 0; ks < 4; ++ks) {
    v8s b0h = *(const v8s*)&O1h[((size_t)(ks * 8 + t0) * 64 + l) * 8];
    v8s b0l = *(const v8s*)&O1l[((size_t)(ks * 8 + t0) * 64 + l) * 8];
    v8s b1h = *(const v8s*)&O1h[((size_t)(ks * 8 + t1) * 64 + l) * 8];
    v8s b1l = *(const v8s*)&O1l[((size_t)(ks * 8 + t1) * 64 + l) * 8];
    acc0 = __builtin_amdgcn_mfma_f32_16x16x32_bf16(a2h[ks], b0h, acc0, 0, 0, 0);
    acc0 = __builtin_amdgcn_mfma_f32_16x16x32_bf16(a2l[ks], b0h, acc0, 0, 0, 0);
    acc0 = __builtin_amdgcn_mfma_f32_16x16x32_bf16(a2h[ks], b0l, acc0, 0, 0, 0);
    acc1 = __builtin_amdgcn_mfma_f32_16x16x32_bf16(a2h[ks], b1h, acc1, 0, 0, 0);
    acc1 = __builtin_amdgcn_mfma_f32_16x16x32_bf16(a2l[ks], b1h, acc1, 0, 0, 0);
    acc1 = __builtin_amdgcn_mfma_f32_16x16x32_bf16(a2h[ks], b1l, acc1, 0, 0, 0);
  }
  {
    const float bb0 = b1[t0 * 16 + cq], bb1 = b1[t1 * 16 + cq];
    #pragma unroll
    for (int r = 0; r < 4; ++r) {
      hS[q * 4 + r][t0 * 16 + cq] = silu_f(acc0[r] + bb0);
      hS[q * 4 + r][t1 * 16 + cq] = silu_f(acc1[r] + bb1);
    }
  }
  __syncthreads();

  #pragma unroll
  for (int ks = 0; ks < 4; ++ks) {
    float4 p0 = *(const float4*)&hS[cq][ks * 32 + q * 8];
    float4 p1 = *(const float4*)&hS[cq][ks * 32 + q * 8 + 4];
    float xv[8] = {p0.x, p0.y, p0.z, p0.w, p1.x, p1.y, p1.z, p1.w};
    #pragma unroll
    for (int j = 0; j < 8; ++j) {
      short hs, ls;
      split_trunc(xv[j], &hs, &ls);
      a2h[ks][j] = hs; a2l[ks][j] = ls;
    }
  }
  acc0 = (v4f){0.f, 0.f, 0.f, 0.f};
  acc1 = (v4f){0.f, 0.f, 0.f, 0.f};
  #pragma unroll
  for (int ks = 0; ks < 4; ++ks) {
    v8s b0h = *(const v8s*)&O2h[((size_t)(ks * 8 + t0) * 64 + l) * 8];
    v8s b0l = *(const v8s*)&O2l[((size_t)(ks * 8 + t0) * 64 + l) * 8];
    v8s b1h = *(const v8s*)&O2h[((size_t)(ks * 8 + t1) * 64 + l) * 8];
    v8s b1l = *(const v8s*)&O2l[((size_t)(ks * 8 + t1) * 64 + l) * 8];
    acc0 = __builtin_amdgcn_mfma_f32_16x16x32_bf16(a2h[ks], b0h, acc0, 0, 0, 0);
    acc0 = __builtin_amdgcn_mfma_f32_16x16x32_bf16(a2l[ks], b0h, acc0, 0, 0, 0);
    acc0 = __builtin_amdgcn_mfma_f32_16x16x32_bf16(a2h[ks], b0l, acc0, 0, 0, 0);
    acc1 = __builtin_amdgcn_mfma_f32_16x16x32_bf16(a2h[ks], b1h, acc1, 0, 0, 0);
    acc1 = __builtin_amdgcn_mfma_f32_16x16x32_bf16(a2l[ks], b1h, acc1, 0, 0, 0);
    acc1 = __builtin_amdgcn_mfma_f32_16x16x32_bf16(a2h[ks], b1l, acc1, 0, 0, 0);
  }
  {
    const float bb0 = b2[t0 * 16 + cq], bb1 = b2[t1 * 16 + cq];
    #pragma unroll
    for (int r = 0; r < 4; ++r) {
      out[(size_t)(r0 + q * 4 + r) * 128 + t0 * 16 + cq] = acc0[r] + bb0;
      out[(size_t)(r0 + q * 4 + r) * 128 + t1 * 16 + cq] = acc1[r] + bb1;
    }
  }
}

// ---------------------------------------------------------------------------
extern "C" void kernel_launch(void* const* d_in, const int* in_sizes, int n_in,
                              void* d_out, int out_size, void* d_ws, size_t ws_size,
                              hipStream_t stream) {
  const float* hf    = (const float*)d_in[0];
  const int*   z     = (const int*)  d_in[1];
  const float* pos   = (const float*)d_in[2];
  const float* e_feat= (const float*)d_in[4];
  const float* z_emb = (const float*)d_in[5];
  const float* vwW0  = (const float*)d_in[6];
  const float* vwb0  = (const float*)d_in[7];
  const float* vwW1  = (const float*)d_in[8];
  const float* vwb1  = (const float*)d_in[9];
  const float* vwW2  = (const float*)d_in[10];
  const float* vwb2  = (const float*)d_in[11];
  const float* scW0  = (const float*)d_in[12];
  const float* scb0  = (const float*)d_in[13];
  const float* scW1  = (const float*)d_in[14];
  const float* scb1  = (const float*)d_in[15];
  const float* scW2  = (const float*)d_in[16];
  const float* scb2  = (const float*)d_in[17];
  const float* oW0   = (const float*)d_in[18];
  const float* ob0   = (const float*)d_in[19];
  const float* oW1   = (const float*)d_in[20];
  const float* ob1   = (const float*)d_in[21];
  const float* oW2   = (const float*)d_in[22];
  const float* ob2   = (const float*)d_in[23];
  float* out = (float*)d_out;

  float* ws = (float*)d_ws;
  unsigned short* W2fh = (unsigned short*)(ws);            // 589824 fl
  unsigned short* W2fl = (unsigned short*)(ws + 589824);   // 589824 fl
  unsigned short* hTh  = (unsigned short*)(ws + 1179648);  // 65536 fl
  unsigned short* hTl  = (unsigned short*)(ws + 1245184);  // 65536 fl
  float* Pn     = ws + 1310720;   // 131072
  float* Pa     = Pn + 131072;    // 2048
  float* Pe     = Pa + 2048;      // 16384
  float* xvu    = Pe + 16384;     // 32768
  float* y1cw   = xvu + 32768;    // 4096
  float* values = y1cw + 4096;    // 163840
  float* invagg = values + 163840;// 196608
  unsigned short* W1fh = (unsigned short*)(invagg + 196608);  // 8192 fl
  unsigned short* W1fl = (unsigned short*)(invagg + 196608 + 8192);
  float* values8 = invagg + 196608 + 16384;  // 8*163840 fl
  unsigned short* Ob = (unsigned short*)(values8 + 8 * 163840);
  unsigned short* O0h = Ob;
  unsigned short* O0l = Ob + 12288;
  unsigned short* O1h = Ob + 24576;
  unsigned short* O1l = Ob + 40960;
  unsigned short* O2h = Ob + 57344;
  unsigned short* O2l = Ob + 73728;

  hipMemsetAsync(values8, 0, 8 * 163840 * sizeof(float), stream);

  k_front<<<1182, 256, 0, stream>>>(
      vwW2, W2fh, W2fl,
      hf, z, pos, z_emb, vwW0, vwb0, vwW1, vwb1, scW0,
      hTh, hTl, Pn, Pa, xvu, y1cw,
      scW1, W1fh, W1fl, oW0, oW1, oW2,
      O0h, O0l, O1h, O1l, O2h, O2l,
      e_feat, scb0, Pe);
  k_tp<<<512, 256, 0, stream>>>(hTh, hTl, W2fh, W2fl, vwb2, hf, xvu,
                                y1cw, values8);
  k_reduce<<<160, 256, 0, stream>>>(values8, values);
  k_gate_agg<<<1024, 256, 0, stream>>>(Pa, Pe, Pn, W1fh, W1fl, scb1, scW2, scb2,
                                       y1cw, values, invagg);
  k_out<<<128, 256, 0, stream>>>(invagg, O0h, O0l, O1h, O1l, O2h, O2l,
                                 ob0, ob1, ob2, out);
}